// Round 8
// baseline (49.888 us; speedup 1.0000x reference)
//
#include <hip/hip_runtime.h>
#include <math.h>

#define NH 8            // heads
#define HD 32           // head dim
#define MD 128          // max dist
#define NW 257          // 2*MD+1
#define NWP 272         // padded to 17*16
#define WSM 64          // smoothed PE width
#define NB 4            // batch
#define NL 2048         // length
#define NC 64           // channels
#define NHD 256         // NH*HD
#define PR 16           // rows per proj block
#define NPROJ_BLK (NB * NL / PR)   // 512
#define SPE_BLK 34                 // 34*256*8 == NH*NWP*HD
#define SP 40           // padded LDS row stride in bf16 elems (80B)
// 32^-0.5 * log2(e): scores land in log2 domain -> exp2f directly
#define SC2 0.2550928063161107f

using bf16x8 = __attribute__((ext_vector_type(8))) short;
using f32x4  = __attribute__((ext_vector_type(4))) float;
using i32x4  = __attribute__((ext_vector_type(4))) int;

__device__ __forceinline__ unsigned short f2bf(float f) {
  unsigned int u = __builtin_bit_cast(unsigned int, f);
  u = (u + 0x7fffu + ((u >> 16) & 1u)) >> 16;
  return (unsigned short)u;
}

// ---- projections (qu=q+u_pe, qv=q+v_pe, k*SC2 as bf16; v=sigmoid f32)
// ---- + trailing blocks: smooth-PE (pre-scaled by SC2) and d_out zeroing
__global__ __launch_bounds__(256) void proj_spe_kernel(
    const float* __restrict__ x,
    const float* __restrict__ Wq, const float* __restrict__ bq,
    const float* __restrict__ Wk, const float* __restrict__ bk,
    const float* __restrict__ Wv, const float* __restrict__ dpe,
    const float* __restrict__ u_pe, const float* __restrict__ v_pe,
    unsigned short* __restrict__ qu, unsigned short* __restrict__ qv,
    unsigned short* __restrict__ kb, float* __restrict__ vv,
    unsigned short* __restrict__ spt, float* __restrict__ out) {
  const int t = threadIdx.x;

  if (blockIdx.x >= NPROJ_BLK) {
    const int base = (blockIdx.x - NPROJ_BLK) * 256 + t;
    // zero the output accumulator (band kernel atomically adds; stream order protects us)
    if (base < NB * NW * NH) out[base] = 0.f;
    // smooth_pe bilinear upsample -> bf16 [h][272][32], pre-scaled, rows 257..271 zeroed
    for (int idx = base; idx < NH * NWP * HD; idx += SPE_BLK * 256) {
      const int d = idx & 31;
      const int hm = idx >> 5;
      const int m = hm % NWP;
      const int h = hm / NWP;
      float val = 0.f;
      if (m < NW) {
        float tt = (m + 0.5f) * ((float)WSM / (float)NW) - 0.5f;
        tt = fminf(fmaxf(tt, 0.f), (float)(WSM - 1));
        const int i0 = (int)tt;
        const float f = tt - (float)i0;
        const int i1 = (i0 + 1 < WSM) ? i0 + 1 : WSM - 1;
        const float* bse = dpe + ((size_t)h * HD + d) * WSM;
        val = (bse[i0] * (1.f - f) + bse[i1] * f) * SC2;
      }
      spt[idx] = f2bf(val);
    }
    return;
  }

  __shared__ float xs[PR][NC];
  const int row0 = blockIdx.x * PR;
  if (t < PR * NC / 4)
    reinterpret_cast<float4*>(xs)[t] = reinterpret_cast<const float4*>(x + (size_t)row0 * NC)[t];
  __syncthreads();

  const int h = t >> 5, d = t & 31;
  const float uu = u_pe[t];   // (H,1,1,D) flat == h*32+d == t
  const float vp = v_pe[t];
  float accq[PR], acck[PR];
  const float bq_t = bq[t], bk_t = bk[t];
#pragma unroll
  for (int r = 0; r < PR; ++r) { accq[r] = bq_t; acck[r] = bk_t; }
#pragma unroll
  for (int c4 = 0; c4 < NC / 4; ++c4) {
    float wq4[4], wk4[4];
#pragma unroll
    for (int j = 0; j < 4; ++j) {
      wq4[j] = Wq[(4 * c4 + j) * NHD + t];
      wk4[j] = Wk[(4 * c4 + j) * NHD + t];
    }
#pragma unroll
    for (int r = 0; r < PR; ++r) {
      const float4 xv = *reinterpret_cast<const float4*>(&xs[r][4 * c4]);
      accq[r] = fmaf(xv.x, wq4[0], accq[r]);
      accq[r] = fmaf(xv.y, wq4[1], accq[r]);
      accq[r] = fmaf(xv.z, wq4[2], accq[r]);
      accq[r] = fmaf(xv.w, wq4[3], accq[r]);
      acck[r] = fmaf(xv.x, wk4[0], acck[r]);
      acck[r] = fmaf(xv.y, wk4[1], acck[r]);
      acck[r] = fmaf(xv.z, wk4[2], acck[r]);
      acck[r] = fmaf(xv.w, wk4[3], acck[r]);
    }
  }
#pragma unroll
  for (int r = 0; r < PR; ++r) {
    const int row = row0 + r;
    const int b = row >> 11, l = row & (NL - 1);
    const size_t o = (((size_t)h * NB + b) * NL + l) * HD + d;
    qu[o] = f2bf(accq[r] + uu);
    qv[o] = f2bf(accq[r] + vp);
    kb[o] = f2bf(acck[r] * SC2);   // softmax scale * log2e folded into k
  }
  if (t < PR * NH) {
    const int r = t >> 3, hh = t & 7;
    float a = 0.f;
#pragma unroll
    for (int c4 = 0; c4 < NC / 4; ++c4) {
      const float4 xv = *reinterpret_cast<const float4*>(&xs[r][4 * c4]);
      a = fmaf(xv.x, Wv[(4 * c4 + 0) * NH + hh], a);
      a = fmaf(xv.y, Wv[(4 * c4 + 1) * NH + hh], a);
      a = fmaf(xv.z, Wv[(4 * c4 + 2) * NH + hh], a);
      a = fmaf(xv.w, Wv[(4 * c4 + 3) * NH + hh], a);
    }
    const int row = row0 + r;
    const int b = row >> 11, l = row & (NL - 1);
    vv[((size_t)hh * NB + b) * NL + l] = 1.f / (1.f + __expf(-a));
  }
}

// ---------- main: qu LDS-staged (batched), sp direct-global (wave-uniform -> L1 broadcast),
// ---------- MFMA band+PE pipeline, no-max exp2 softmax, rcp, gate, reduce ----------
__global__ __launch_bounds__(256, 4) void band_attn_mfma(
    const unsigned short* __restrict__ qu, const unsigned short* __restrict__ qv,
    const unsigned short* __restrict__ kb, const float* __restrict__ vv,
    const unsigned short* __restrict__ spt, float* __restrict__ out) {
  __shared__ __align__(16) unsigned short qu_sh[320 * SP];  // qu window, stride-40 padded
  float* red = reinterpret_cast<float*>(qu_sh);             // overlay after barrier

  const int bid = blockIdx.x;
  const int tile = bid & 31;
  const int hb = bid >> 5;            // h*NB + b
  const int b = hb & (NB - 1);
  const int h = hb >> 2;
  const int n0 = tile << 6;
  const int jlo = NL - 64 - n0;       // k rows jlo..jlo+63 (i ascending)
  const int tid = threadIdx.x;
  const int l = tid & 63;
  const int w = tid >> 6;             // wave: rows i = 16w..16w+15
  const int c = l & 15;               // fragment row/col index
  const int g = l >> 4;               // k-chunk group
  const int g8 = g * 8;               // element offset of the 16B chunk

  const unsigned short* qu_h = qu + (size_t)hb * NL * HD;
  const unsigned short* qv_h = qv + (size_t)hb * NL * HD;
  const unsigned short* k_h  = kb + (size_t)hb * NL * HD;
  const unsigned short* sp_h = spt + (size_t)h * NWP * HD;
  const float* vv_h = vv + (size_t)hb * NL;

  // A fragments + v-gate direct from global, issued BEFORE staging (latency hides under it).
  const bf16x8 ak  = *reinterpret_cast<const bf16x8*>(k_h  + (size_t)(jlo + 16 * w + c) * HD + g8);
  const bf16x8 aqv = *reinterpret_cast<const bf16x8*>(qv_h + (size_t)(n0 + 63 - 16 * w - c) * HD + g8);
  const f32x4 v4 = *reinterpret_cast<const f32x4*>(vv_h + (n0 + 60 - 16 * w - 4 * g));

  // ---- qu staging, batched: ALL global loads into regs, THEN all ds_writes (one RTT).
  const int wq0_blk = jlo - MD;       // global row of qu_sh row 0 (may be <0)
  i32x4 stq[5];
#pragma unroll
  for (int it = 0; it < 5; ++it) {
    const int p = tid + it * 256;
    const int gr = wq0_blk + (p >> 2);
    i32x4 val = {0, 0, 0, 0};
    if ((unsigned)gr < (unsigned)NL)
      val = *reinterpret_cast<const i32x4*>(qu_h + (size_t)gr * HD + (p & 3) * 8);
    stq[it] = val;
  }
#pragma unroll
  for (int it = 0; it < 5; ++it) {
    const int p = tid + it * 256;
    *reinterpret_cast<i32x4*>(&qu_sh[(p >> 2) * SP + (p & 3) * 8]) = stq[it];
  }
  __syncthreads();

  const f32x4 z4 = {0.f, 0.f, 0.f, 0.f};

  // realign constants: C/D layout row=(l>>4)*4+reg, col=l&15 (m89-verified);
  // source col = (4g+r-c)&15 (tile-independent), pick tile 16-t vs 15-t by cond.
  int sl[4]; bool cond[4];
#pragma unroll
  for (int r = 0; r < 4; ++r) {
    sl[r] = 16 * g + ((4 * g + r - c) & 15);
    cond[r] = (4 * g + r) >= c;
  }

  f32x4 s[17];
  f32x4 shp;
  // Fused pipeline: step U computes PE tile t=16-U and band tile T=U, finalizes s[16-U].
  // kb and spt are pre-scaled by 32^-0.5*log2e, so s is the log2-domain score directly.
  // sp rows are identical across all 4 waves -> L1 broadcast, no staging needed.
#pragma unroll
  for (int U = 0; U <= 16; ++U) {
    const int tpe = 16 - U;
    const bf16x8 bsp = *reinterpret_cast<const bf16x8*>(sp_h + (size_t)(16 * tpe + c) * HD + g8);
    const f32x4 spe = __builtin_amdgcn_mfma_f32_16x16x32_bf16(aqv, bsp, z4, 0, 0, 0);

    const bf16x8 bqu = *reinterpret_cast<const bf16x8*>(&qu_sh[(16 * w + 16 * U + c) * SP + g8]);
    const f32x4 c1 = __builtin_amdgcn_mfma_f32_16x16x32_bf16(ak, bqu, z4, 0, 0, 0);

    f32x4 shc;
#pragma unroll
    for (int r = 0; r < 4; ++r) shc[r] = __shfl(c1[r], sl[r], 64);

    if (U == 0) {
#pragma unroll
      for (int r = 0; r < 4; ++r)
        s[16][r] = (c == 0) ? (shc[r] + spe[r]) : -1e30f;  // m=256+c valid only c==0
    } else {
#pragma unroll
      for (int r = 0; r < 4; ++r) {
        const float band = cond[r] ? shc[r] : shp[r];
        s[tpe][r] = band + spe[r];
      }
    }
    shp = shc;
  }

  // per-row softmax, NO max-subtraction (|scores| ~ 1, exact in f32), exp2 domain.
  float wgt[4];
#pragma unroll
  for (int r = 0; r < 4; ++r) {
    float sum = 0.f;
#pragma unroll
    for (int t = 0; t < 17; ++t) {
      const float p = exp2f(s[t][r]);
      s[t][r] = p;
      sum += p;
    }
#pragma unroll
    for (int off = 1; off < 16; off <<= 1) sum += __shfl_xor(sum, off, 16);
    wgt[r] = v4[3 - r] * __builtin_amdgcn_rcpf(sum);  // v[n]/sum via v_rcp (1ulp-ish, fine)
  }

  // out[m] += sum_i p * w : regs -> cross-group -> cross-wave (LDS) -> atomics
  __syncthreads();  // all waves done reading qu_sh; reuse as reduction buffer
#pragma unroll
  for (int t = 0; t < 17; ++t) {
    float y = s[t][0] * wgt[0] + s[t][1] * wgt[1] + s[t][2] * wgt[2] + s[t][3] * wgt[3];
    y += __shfl_xor(y, 16, 64);
    y += __shfl_xor(y, 32, 64);
    if (l < 16) red[w * NWP + 16 * t + c] = y;
  }
  __syncthreads();
  for (int m = tid; m < NW; m += 256) {
    const float ssum = red[m] + red[NWP + m] + red[2 * NWP + m] + red[3 * NWP + m];
    atomicAdd(&out[((size_t)b * NW + m) * NH + h], ssum);
  }
}

extern "C" void kernel_launch(void* const* d_in, const int* in_sizes, int n_in,
                              void* d_out, int out_size, void* d_ws, size_t ws_size,
                              hipStream_t stream) {
  const float* x = (const float*)d_in[0];
  const float* Wq = (const float*)d_in[1];
  const float* bq = (const float*)d_in[2];
  const float* Wk = (const float*)d_in[3];
  const float* bk = (const float*)d_in[4];
  const float* Wv = (const float*)d_in[5];
  const float* dpe = (const float*)d_in[6];
  const float* u_pe = (const float*)d_in[7];
  const float* v_pe = (const float*)d_in[8];
  float* out = (float*)d_out;

  const size_t qk_elems = (size_t)NH * NB * NL * HD;  // 2,097,152
  float* vv = (float*)d_ws;                           // 65,536 f32
  unsigned short* qu = (unsigned short*)(vv + (size_t)NH * NB * NL);
  unsigned short* qv = qu + qk_elems;
  unsigned short* kb = qv + qk_elems;
  unsigned short* spt = kb + qk_elems;                // 8*272*32

  hipLaunchKernelGGL(proj_spe_kernel, dim3(NPROJ_BLK + SPE_BLK), dim3(256), 0, stream,
                     x, Wq, bq, Wk, bk, Wv, dpe, u_pe, v_pe, qu, qv, kb, vv, spt, out);
  hipLaunchKernelGGL(band_attn_mfma, dim3(NH * NB * 32), dim3(256), 0, stream,
                     qu, qv, kb, vv, spt, out);
}

// Round 9
// 38.687 us; speedup vs baseline: 1.2895x; 1.2895x over previous
//
#include <hip/hip_runtime.h>
#include <math.h>

#define NH 8            // heads
#define HD 32           // head dim
#define MD 128          // max dist
#define NW 257          // 2*MD+1
#define NWP 272         // padded to 17*16
#define WSM 64          // smoothed PE width
#define NB 4            // batch
#define NL 2048         // length
#define NC 64           // channels
#define NHD 256         // NH*HD
#define PR 8            // rows per proj block
#define NPROJ_BLK (NB * NL / PR)   // 1024
#define SPE_BLK 34                 // 34*256*8 == NH*NWP*HD
#define SP 40           // padded LDS row stride in bf16 elems (80B)
#define ROWS 128        // output rows per band block
#define WIN 384         // ROWS + 2*MD
// 32^-0.5 * log2(e): scores land in log2 domain -> exp2f directly
#define SC2 0.2550928063161107f

using bf16x8 = __attribute__((ext_vector_type(8))) short;
using f32x4  = __attribute__((ext_vector_type(4))) float;
using i32x4  = __attribute__((ext_vector_type(4))) int;

__device__ __forceinline__ unsigned short f2bf(float f) {
  unsigned int u = __builtin_bit_cast(unsigned int, f);
  u = (u + 0x7fffu + ((u >> 16) & 1u)) >> 16;
  return (unsigned short)u;
}

// ---- projections (qu=q+u_pe, qv=q+v_pe, k*SC2 as bf16; v=sigmoid f32)
// ---- + trailing blocks: smooth-PE (pre-scaled by SC2) and d_out zeroing
__global__ __launch_bounds__(256) void proj_spe_kernel(
    const float* __restrict__ x,
    const float* __restrict__ Wq, const float* __restrict__ bq,
    const float* __restrict__ Wk, const float* __restrict__ bk,
    const float* __restrict__ Wv, const float* __restrict__ dpe,
    const float* __restrict__ u_pe, const float* __restrict__ v_pe,
    unsigned short* __restrict__ qu, unsigned short* __restrict__ qv,
    unsigned short* __restrict__ kb, float* __restrict__ vv,
    unsigned short* __restrict__ spt, float* __restrict__ out) {
  const int t = threadIdx.x;

  if (blockIdx.x >= NPROJ_BLK) {
    const int base = (blockIdx.x - NPROJ_BLK) * 256 + t;
    // zero the output accumulator (band kernel atomically adds; stream order protects us)
    if (base < NB * NW * NH) out[base] = 0.f;
    // smooth_pe bilinear upsample -> bf16 [h][272][32], pre-scaled, rows 257..271 zeroed
    for (int idx = base; idx < NH * NWP * HD; idx += SPE_BLK * 256) {
      const int d = idx & 31;
      const int hm = idx >> 5;
      const int m = hm % NWP;
      const int h = hm / NWP;
      float val = 0.f;
      if (m < NW) {
        float tt = (m + 0.5f) * ((float)WSM / (float)NW) - 0.5f;
        tt = fminf(fmaxf(tt, 0.f), (float)(WSM - 1));
        const int i0 = (int)tt;
        const float f = tt - (float)i0;
        const int i1 = (i0 + 1 < WSM) ? i0 + 1 : WSM - 1;
        const float* bse = dpe + ((size_t)h * HD + d) * WSM;
        val = (bse[i0] * (1.f - f) + bse[i1] * f) * SC2;
      }
      spt[idx] = f2bf(val);
    }
    return;
  }

  __shared__ float xs[PR][NC];
  const int row0 = blockIdx.x * PR;
  if (t < PR * NC / 4)
    reinterpret_cast<float4*>(xs)[t] = reinterpret_cast<const float4*>(x + (size_t)row0 * NC)[t];
  __syncthreads();

  const int h = t >> 5, d = t & 31;
  const float uu = u_pe[t];   // (H,1,1,D) flat == h*32+d == t
  const float vp = v_pe[t];
  float accq[PR], acck[PR];
  const float bq_t = bq[t], bk_t = bk[t];
#pragma unroll
  for (int r = 0; r < PR; ++r) { accq[r] = bq_t; acck[r] = bk_t; }
#pragma unroll
  for (int c4 = 0; c4 < NC / 4; ++c4) {
    float wq4[4], wk4[4];
#pragma unroll
    for (int j = 0; j < 4; ++j) {
      wq4[j] = Wq[(4 * c4 + j) * NHD + t];
      wk4[j] = Wk[(4 * c4 + j) * NHD + t];
    }
#pragma unroll
    for (int r = 0; r < PR; ++r) {
      const float4 xv = *reinterpret_cast<const float4*>(&xs[r][4 * c4]);
      accq[r] = fmaf(xv.x, wq4[0], accq[r]);
      accq[r] = fmaf(xv.y, wq4[1], accq[r]);
      accq[r] = fmaf(xv.z, wq4[2], accq[r]);
      accq[r] = fmaf(xv.w, wq4[3], accq[r]);
      acck[r] = fmaf(xv.x, wk4[0], acck[r]);
      acck[r] = fmaf(xv.y, wk4[1], acck[r]);
      acck[r] = fmaf(xv.z, wk4[2], acck[r]);
      acck[r] = fmaf(xv.w, wk4[3], acck[r]);
    }
  }
#pragma unroll
  for (int r = 0; r < PR; ++r) {
    const int row = row0 + r;
    const int b = row >> 11, l = row & (NL - 1);
    const size_t o = (((size_t)h * NB + b) * NL + l) * HD + d;
    qu[o] = f2bf(accq[r] + uu);
    qv[o] = f2bf(accq[r] + vp);
    kb[o] = f2bf(acck[r] * SC2);   // softmax scale * log2e folded into k
  }
  if (t < PR * NH) {
    const int r = t >> 3, hh = t & 7;
    float a = 0.f;
#pragma unroll
    for (int c4 = 0; c4 < NC / 4; ++c4) {
      const float4 xv = *reinterpret_cast<const float4*>(&xs[r][4 * c4]);
      a = fmaf(xv.x, Wv[(4 * c4 + 0) * NH + hh], a);
      a = fmaf(xv.y, Wv[(4 * c4 + 1) * NH + hh], a);
      a = fmaf(xv.z, Wv[(4 * c4 + 2) * NH + hh], a);
      a = fmaf(xv.w, Wv[(4 * c4 + 3) * NH + hh], a);
    }
    const int row = row0 + r;
    const int b = row >> 11, l = row & (NL - 1);
    vv[((size_t)hh * NB + b) * NL + l] = 1.f / (1.f + __expf(-a));
  }
}

// ---------- main: 128-row tiles, 8 waves. PE MFMAs run pre-barrier (direct-global sp,
// ---------- latency-hidden vs qu staging); band MFMAs post-barrier from LDS.
__global__ __launch_bounds__(512, 4) void band_attn_mfma(
    const unsigned short* __restrict__ qu, const unsigned short* __restrict__ qv,
    const unsigned short* __restrict__ kb, const float* __restrict__ vv,
    const unsigned short* __restrict__ spt, float* __restrict__ out) {
  __shared__ __align__(16) unsigned short qu_sh[WIN * SP];  // 384 rows, stride-40: 30.7 KB
  float* red = reinterpret_cast<float*>(qu_sh);             // overlay (8*NWP*4 = 8.7 KB)

  const int bid = blockIdx.x;
  const int tile = bid & 15;          // 16 tiles of 128 rows
  const int hb = bid >> 4;            // h*NB + b
  const int b = hb & (NB - 1);
  const int h = hb >> 2;
  const int n0 = tile << 7;
  const int jlo = NL - ROWS - n0;     // k rows jlo..jlo+127
  const int tid = threadIdx.x;
  const int l = tid & 63;
  const int w = tid >> 6;             // wave 0..7: k-row group jj = 16w..16w+15
  const int c = l & 15;
  const int g = l >> 4;
  const int g8 = g * 8;

  const unsigned short* qu_h = qu + (size_t)hb * NL * HD;
  const unsigned short* qv_h = qv + (size_t)hb * NL * HD;
  const unsigned short* k_h  = kb + (size_t)hb * NL * HD;
  const unsigned short* sp_h = spt + (size_t)h * NWP * HD;
  const float* vv_h = vv + (size_t)hb * NL;

  // A fragments + v-gate (global, earliest issue)
  const bf16x8 ak  = *reinterpret_cast<const bf16x8*>(k_h  + (size_t)(jlo + 16 * w + c) * HD + g8);
  const bf16x8 aqv = *reinterpret_cast<const bf16x8*>(qv_h + (size_t)(n0 + 127 - 16 * w - c) * HD + g8);
  const f32x4 v4 = *reinterpret_cast<const f32x4*>(vv_h + (n0 + 124 - 16 * w - 4 * g));

  // qu staging loads issued BEFORE the PE chain (their RTT completes under PE compute)
  const int wq0_blk = jlo - MD;       // global row of qu_sh row 0 (may be <0)
  i32x4 stq[3];
#pragma unroll
  for (int it = 0; it < 3; ++it) {    // 384 rows * 4 chunks / 512 threads
    const int p = tid + it * 512;
    const int gr = wq0_blk + (p >> 2);
    i32x4 val = {0, 0, 0, 0};
    if ((unsigned)gr < (unsigned)NL)
      val = *reinterpret_cast<const i32x4*>(qu_h + (size_t)gr * HD + (p & 3) * 8);
    stq[it] = val;
  }

  const f32x4 z4 = {0.f, 0.f, 0.f, 0.f};

  // ---- PE term pre-barrier: s[t] = aqv . sp[16t+c]  (17 independent global loads, 1 RTT;
  // sp rows identical across all 8 waves -> L1 broadcast). Runs while staging completes.
  f32x4 s[17];
#pragma unroll
  for (int t = 0; t < 17; ++t) {
    const bf16x8 bsp = *reinterpret_cast<const bf16x8*>(sp_h + (size_t)(16 * t + c) * HD + g8);
    s[t] = __builtin_amdgcn_mfma_f32_16x16x32_bf16(aqv, bsp, z4, 0, 0, 0);
  }

  // complete staging: ds_writes + barrier
#pragma unroll
  for (int it = 0; it < 3; ++it) {
    const int p = tid + it * 512;
    *reinterpret_cast<i32x4*>(&qu_sh[(p >> 2) * SP + (p & 3) * 8]) = stq[it];
  }
  __syncthreads();

  // realign constants: C/D layout row=(l>>4)*4+reg, col=l&15 (m89-verified);
  // source col = (4g+r-c)&15 (tile-independent), pick tile 16-t vs 15-t by cond.
  int sl[4]; bool cond[4];
#pragma unroll
  for (int r = 0; r < 4; ++r) {
    sl[r] = 16 * g + ((4 * g + r - c) & 15);
    cond[r] = (4 * g + r) >= c;
  }

  // ---- band term post-barrier: step U computes j-space tile T=U, folds into s[16-U].
  f32x4 shp;
#pragma unroll
  for (int U = 0; U <= 16; ++U) {
    const bf16x8 bqu = *reinterpret_cast<const bf16x8*>(&qu_sh[(16 * w + 16 * U + c) * SP + g8]);
    const f32x4 c1 = __builtin_amdgcn_mfma_f32_16x16x32_bf16(ak, bqu, z4, 0, 0, 0);

    f32x4 shc;
#pragma unroll
    for (int r = 0; r < 4; ++r) shc[r] = __shfl(c1[r], sl[r], 64);

    if (U == 0) {
#pragma unroll
      for (int r = 0; r < 4; ++r)
        s[16][r] = (c == 0) ? (s[16][r] + shc[r]) : -1e30f;  // m=256+c valid only c==0
    } else {
#pragma unroll
      for (int r = 0; r < 4; ++r)
        s[16 - U][r] += cond[r] ? shc[r] : shp[r];
    }
    shp = shc;
  }

  // per-row softmax, NO max-subtraction (|scores| ~ 1, exact in f32), exp2 domain.
  float wgt[4];
#pragma unroll
  for (int r = 0; r < 4; ++r) {
    float sum = 0.f;
#pragma unroll
    for (int t = 0; t < 17; ++t) {
      const float p = exp2f(s[t][r]);
      s[t][r] = p;
      sum += p;
    }
#pragma unroll
    for (int off = 1; off < 16; off <<= 1) sum += __shfl_xor(sum, off, 16);
    wgt[r] = v4[3 - r] * __builtin_amdgcn_rcpf(sum);  // v[n]/sum, n = n0+127-(16w+4g+r)
  }

  // out[m] += sum_i p * w : regs -> cross-group -> cross-wave (LDS) -> atomics
  __syncthreads();  // all waves done reading qu_sh; reuse as reduction buffer
#pragma unroll
  for (int t = 0; t < 17; ++t) {
    float y = s[t][0] * wgt[0] + s[t][1] * wgt[1] + s[t][2] * wgt[2] + s[t][3] * wgt[3];
    y += __shfl_xor(y, 16, 64);
    y += __shfl_xor(y, 32, 64);
    if (l < 16) red[w * NWP + 16 * t + c] = y;
  }
  __syncthreads();
  for (int m = tid; m < NW; m += 512) {
    float ssum = 0.f;
#pragma unroll
    for (int ww = 0; ww < 8; ++ww) ssum += red[ww * NWP + m];
    atomicAdd(&out[((size_t)b * NW + m) * NH + h], ssum);
  }
}

extern "C" void kernel_launch(void* const* d_in, const int* in_sizes, int n_in,
                              void* d_out, int out_size, void* d_ws, size_t ws_size,
                              hipStream_t stream) {
  const float* x = (const float*)d_in[0];
  const float* Wq = (const float*)d_in[1];
  const float* bq = (const float*)d_in[2];
  const float* Wk = (const float*)d_in[3];
  const float* bk = (const float*)d_in[4];
  const float* Wv = (const float*)d_in[5];
  const float* dpe = (const float*)d_in[6];
  const float* u_pe = (const float*)d_in[7];
  const float* v_pe = (const float*)d_in[8];
  float* out = (float*)d_out;

  const size_t qk_elems = (size_t)NH * NB * NL * HD;  // 2,097,152
  float* vv = (float*)d_ws;                           // 65,536 f32
  unsigned short* qu = (unsigned short*)(vv + (size_t)NH * NB * NL);
  unsigned short* qv = qu + qk_elems;
  unsigned short* kb = qv + qk_elems;
  unsigned short* spt = kb + qk_elems;                // 8*272*32

  hipLaunchKernelGGL(proj_spe_kernel, dim3(NPROJ_BLK + SPE_BLK), dim3(256), 0, stream,
                     x, Wq, bq, Wk, bk, Wv, dpe, u_pe, v_pe, qu, qv, kb, vv, spt, out);
  hipLaunchKernelGGL(band_attn_mfma, dim3(NH * NB * (NL / ROWS)), dim3(512), 0, stream,
                     qu, qv, kb, vv, spt, out);
}

// Round 10
// 36.902 us; speedup vs baseline: 1.3519x; 1.0484x over previous
//
#include <hip/hip_runtime.h>
#include <math.h>

#define NH 8            // heads
#define HD 32           // head dim
#define MD 128          // max dist
#define NW 257          // 2*MD+1
#define NWP 272         // padded to 17*16
#define WSM 64          // smoothed PE width
#define NB 4            // batch
#define NL 2048         // length
#define NC 64           // channels
#define NHD 256         // NH*HD
#define SP 40           // padded LDS row stride in bf16 elems (80B)
#define ROWS 256        // output rows per band block
#define WIN 512         // ROWS + 2*MD
// 32^-0.5 * log2(e): scores land in log2 domain -> exp2f directly
#define SC2 0.2550928063161107f

#define PM_BLK 512      // MFMA proj blocks: 128 row-tiles x 4 col-tiles
#define VV_BLK 64       // sigmoid-v tail blocks (128 rows each)
#define SPE_BLK 34      // smooth-PE + out-zero tail blocks

using bf16x8 = __attribute__((ext_vector_type(8))) short;
using f32x4  = __attribute__((ext_vector_type(4))) float;
using i32x4  = __attribute__((ext_vector_type(4))) int;

__device__ __forceinline__ unsigned cvtpk(float lo, float hi) {
  unsigned r;
  asm("v_cvt_pk_bf16_f32 %0, %1, %2" : "=v"(r) : "v"(lo), "v"(hi));
  return r;
}
__device__ __forceinline__ void stb(unsigned short* p, float f) {
  *p = (unsigned short)cvtpk(f, f);   // RNE bf16, low half
}

// ---- MFMA projections (qu=q+u_pe, qv=q+v_pe, kb=k*SC2 bf16) + tails: vv sigmoid,
// ---- smooth-PE table (pre-scaled), d_out zeroing. All tail outputs feed the NEXT launch.
__global__ __launch_bounds__(256, 4) void projmm_kernel(
    const float* __restrict__ x,
    const float* __restrict__ Wq, const float* __restrict__ bq,
    const float* __restrict__ Wk, const float* __restrict__ bk,
    const float* __restrict__ Wv, const float* __restrict__ dpe,
    const float* __restrict__ u_pe, const float* __restrict__ v_pe,
    unsigned short* __restrict__ qu, unsigned short* __restrict__ qv,
    unsigned short* __restrict__ kb, float* __restrict__ vv,
    unsigned short* __restrict__ spt, float* __restrict__ out) {
  const int t = threadIdx.x;
  const int bid = blockIdx.x;

  if (bid >= PM_BLK + VV_BLK) {
    // ---- spe + zero-out tail ----
    const int base = (bid - PM_BLK - VV_BLK) * 256 + t;
    if (base < NB * NW * NH) out[base] = 0.f;
    for (int idx = base; idx < NH * NWP * HD; idx += SPE_BLK * 256) {
      const int d = idx & 31;
      const int hm = idx >> 5;
      const int m = hm % NWP;
      const int h = hm / NWP;
      float val = 0.f;
      if (m < NW) {
        float tt = (m + 0.5f) * ((float)WSM / (float)NW) - 0.5f;
        tt = fminf(fmaxf(tt, 0.f), (float)(WSM - 1));
        const int i0 = (int)tt;
        const float f = tt - (float)i0;
        const int i1 = (i0 + 1 < WSM) ? i0 + 1 : WSM - 1;
        const float* bse = dpe + ((size_t)h * HD + d) * WSM;
        val = (bse[i0] * (1.f - f) + bse[i1] * f) * SC2;
      }
      stb(spt + idx, val);
    }
    return;
  }

  if (bid >= PM_BLK) {
    // ---- vv tail: v = sigmoid(x @ Wv), 128 rows/block, 2 threads/row x 4 heads ----
    const int row = (bid - PM_BLK) * 128 + (t >> 1);
    const int h0 = (t & 1) * 4;
    const float* xr = x + (size_t)row * NC;
    float a0 = 0.f, a1 = 0.f, a2 = 0.f, a3 = 0.f;
#pragma unroll
    for (int c4 = 0; c4 < NC / 4; ++c4) {
      const float4 xv = *reinterpret_cast<const float4*>(xr + 4 * c4);
#pragma unroll
      for (int j = 0; j < 4; ++j) {
        const float xs = j == 0 ? xv.x : j == 1 ? xv.y : j == 2 ? xv.z : xv.w;
        const float4 wv = *reinterpret_cast<const float4*>(Wv + (4 * c4 + j) * NH + h0);
        a0 = fmaf(xs, wv.x, a0);
        a1 = fmaf(xs, wv.y, a1);
        a2 = fmaf(xs, wv.z, a2);
        a3 = fmaf(xs, wv.w, a3);
      }
    }
    const int b = row >> 11, ll = row & (NL - 1);
    vv[((size_t)(h0 + 0) * NB + b) * NL + ll] = 1.f / (1.f + __expf(-a0));
    vv[((size_t)(h0 + 1) * NB + b) * NL + ll] = 1.f / (1.f + __expf(-a1));
    vv[((size_t)(h0 + 2) * NB + b) * NL + ll] = 1.f / (1.f + __expf(-a2));
    vv[((size_t)(h0 + 3) * NB + b) * NL + ll] = 1.f / (1.f + __expf(-a3));
    return;
  }

  // ---- MFMA proj: block = 64 rows x 128 cols of the 512-wide concat(q,k) output ----
  const int l64 = t & 63, w = t >> 6;
  const int c = l64 & 15, g = l64 >> 4, g8 = g * 8;
  const int br = bid >> 2;
  const int c0 = (bid & 3) << 7;       // 0,128 -> q cols; 256,384 -> k cols (block-uniform)
  const int r0 = br << 6;
  const int b = r0 >> 11;
  const int l0 = r0 & (NL - 1);

  // A fragments: x rows (fp32 -> bf16 in-register); lane c = row, g = k-chunk
  const float* xr = x + (size_t)(r0 + 16 * w + c) * NC;
  const float4 x00 = *reinterpret_cast<const float4*>(xr + g8);
  const float4 x01 = *reinterpret_cast<const float4*>(xr + g8 + 4);
  const float4 x10 = *reinterpret_cast<const float4*>(xr + 32 + g8);
  const float4 x11 = *reinterpret_cast<const float4*>(xr + 32 + g8 + 4);
  const i32x4 a0i = {(int)cvtpk(x00.x, x00.y), (int)cvtpk(x00.z, x00.w),
                     (int)cvtpk(x01.x, x01.y), (int)cvtpk(x01.z, x01.w)};
  const i32x4 a1i = {(int)cvtpk(x10.x, x10.y), (int)cvtpk(x10.z, x10.w),
                     (int)cvtpk(x11.x, x11.y), (int)cvtpk(x11.z, x11.w)};
  const bf16x8 a0 = __builtin_bit_cast(bf16x8, a0i);
  const bf16x8 a1 = __builtin_bit_cast(bf16x8, a1i);

  const bool isQ = (c0 < 256);
  const float* Wsrc = isQ ? Wq : Wk;
  const int cb = isQ ? c0 : c0 - 256;

  f32x4 acc[8];
#pragma unroll
  for (int tt = 0; tt < 8; ++tt) acc[tt] = {0.f, 0.f, 0.f, 0.f};

#pragma unroll
  for (int tt = 0; tt < 8; ++tt) {
    const float* wp = Wsrc + cb + 16 * tt + c;   // column; row stride NHD (coalesced over c)
    float f0[8], f1[8];
#pragma unroll
    for (int j = 0; j < 8; ++j) {
      f0[j] = wp[(g8 + j) * NHD];
      f1[j] = wp[(32 + g8 + j) * NHD];
    }
    const i32x4 b0i = {(int)cvtpk(f0[0], f0[1]), (int)cvtpk(f0[2], f0[3]),
                       (int)cvtpk(f0[4], f0[5]), (int)cvtpk(f0[6], f0[7])};
    const i32x4 b1i = {(int)cvtpk(f1[0], f1[1]), (int)cvtpk(f1[2], f1[3]),
                       (int)cvtpk(f1[4], f1[5]), (int)cvtpk(f1[6], f1[7])};
    acc[tt] = __builtin_amdgcn_mfma_f32_16x16x32_bf16(a0, __builtin_bit_cast(bf16x8, b0i), acc[tt], 0, 0, 0);
    acc[tt] = __builtin_amdgcn_mfma_f32_16x16x32_bf16(a1, __builtin_bit_cast(bf16x8, b1i), acc[tt], 0, 0, 0);
  }

  // epilogue: D row = 4g+r (x-row within wave tile), col = c (m89-verified layout)
#pragma unroll
  for (int tt = 0; tt < 8; ++tt) {
    const int col = cb + 16 * tt + c;
    const int h = col >> 5, d = col & 31;
    const size_t rowbase = (((size_t)h * NB + b) * NL + l0 + 16 * w) * HD + d;
    if (isQ) {
      const float bias = bq[col];
      const float uu = u_pe[col], vp = v_pe[col];
#pragma unroll
      for (int r = 0; r < 4; ++r) {
        const float val = acc[tt][r] + bias;
        stb(qu + rowbase + (size_t)(4 * g + r) * HD, val + uu);
        stb(qv + rowbase + (size_t)(4 * g + r) * HD, val + vp);
      }
    } else {
      const float bias = bk[col];
#pragma unroll
      for (int r = 0; r < 4; ++r)
        stb(kb + rowbase + (size_t)(4 * g + r) * HD, (acc[tt][r] + bias) * SC2);
    }
  }
}

// ---------- main: 256-row tiles, 16 waves (1 block/CU). PE MFMAs pre-barrier
// ---------- (direct-global sp, latency-hidden vs qu staging); band post-barrier from LDS.
__global__ __launch_bounds__(1024, 4) void band_attn_mfma(
    const unsigned short* __restrict__ qu, const unsigned short* __restrict__ qv,
    const unsigned short* __restrict__ kb, const float* __restrict__ vv,
    const unsigned short* __restrict__ spt, float* __restrict__ out) {
  __shared__ __align__(16) unsigned short qu_sh[WIN * SP];  // 512 rows, stride-40: 40 KB
  float* red = reinterpret_cast<float*>(qu_sh);             // overlay (16*NWP*4 = 17.4 KB)

  const int bid = blockIdx.x;
  const int tile = bid & 7;           // 8 tiles of 256 rows
  const int hb = bid >> 3;            // h*NB + b
  const int b = hb & (NB - 1);
  const int h = hb >> 2;
  const int n0 = tile << 8;
  const int jlo = NL - ROWS - n0;     // k rows jlo..jlo+255
  const int tid = threadIdx.x;
  const int l = tid & 63;
  const int w = tid >> 6;             // wave 0..15: k-row group 16w..16w+15
  const int c = l & 15;
  const int g = l >> 4;
  const int g8 = g * 8;

  const unsigned short* qu_h = qu + (size_t)hb * NL * HD;
  const unsigned short* qv_h = qv + (size_t)hb * NL * HD;
  const unsigned short* k_h  = kb + (size_t)hb * NL * HD;
  const unsigned short* sp_h = spt + (size_t)h * NWP * HD;
  const float* vv_h = vv + (size_t)hb * NL;

  // A fragments + v-gate (global, earliest issue)
  const bf16x8 ak  = *reinterpret_cast<const bf16x8*>(k_h  + (size_t)(jlo + 16 * w + c) * HD + g8);
  const bf16x8 aqv = *reinterpret_cast<const bf16x8*>(qv_h + (size_t)(n0 + 255 - 16 * w - c) * HD + g8);
  const f32x4 v4 = *reinterpret_cast<const f32x4*>(vv_h + (n0 + 252 - 16 * w - 4 * g));

  // qu staging loads issued BEFORE the PE chain (their RTT completes under PE compute)
  const int wq0_blk = jlo - MD;       // global row of qu_sh row 0 (may be <0)
  i32x4 stq[2];
#pragma unroll
  for (int it = 0; it < 2; ++it) {    // 512 rows * 4 chunks / 1024 threads
    const int p = tid + it * 1024;
    const int gr = wq0_blk + (p >> 2);
    i32x4 val = {0, 0, 0, 0};
    if ((unsigned)gr < (unsigned)NL)
      val = *reinterpret_cast<const i32x4*>(qu_h + (size_t)gr * HD + (p & 3) * 8);
    stq[it] = val;
  }

  const f32x4 z4 = {0.f, 0.f, 0.f, 0.f};

  // ---- PE term pre-barrier: s[t] = aqv . sp[16t+c] (17 loads, 1 RTT, L1 broadcast)
  f32x4 s[17];
#pragma unroll
  for (int t = 0; t < 17; ++t) {
    const bf16x8 bsp = *reinterpret_cast<const bf16x8*>(sp_h + (size_t)(16 * t + c) * HD + g8);
    s[t] = __builtin_amdgcn_mfma_f32_16x16x32_bf16(aqv, bsp, z4, 0, 0, 0);
  }

  // complete staging: ds_writes + barrier
#pragma unroll
  for (int it = 0; it < 2; ++it) {
    const int p = tid + it * 1024;
    *reinterpret_cast<i32x4*>(&qu_sh[(p >> 2) * SP + (p & 3) * 8]) = stq[it];
  }
  __syncthreads();

  // realign constants: C/D layout row=(l>>4)*4+reg, col=l&15 (m89-verified);
  // source col = (4g+r-c)&15 (tile-independent), pick tile 16-t vs 15-t by cond.
  int sl[4]; bool cond[4];
#pragma unroll
  for (int r = 0; r < 4; ++r) {
    sl[r] = 16 * g + ((4 * g + r - c) & 15);
    cond[r] = (4 * g + r) >= c;
  }

  // ---- band term post-barrier: step U computes j-space tile T=U, folds into s[16-U].
  f32x4 shp;
#pragma unroll
  for (int U = 0; U <= 16; ++U) {
    const bf16x8 bqu = *reinterpret_cast<const bf16x8*>(&qu_sh[(16 * w + 16 * U + c) * SP + g8]);
    const f32x4 c1 = __builtin_amdgcn_mfma_f32_16x16x32_bf16(ak, bqu, z4, 0, 0, 0);

    f32x4 shc;
#pragma unroll
    for (int r = 0; r < 4; ++r) shc[r] = __shfl(c1[r], sl[r], 64);

    if (U == 0) {
#pragma unroll
      for (int r = 0; r < 4; ++r)
        s[16][r] = (c == 0) ? (s[16][r] + shc[r]) : -1e30f;  // m=256+c valid only c==0
    } else {
#pragma unroll
      for (int r = 0; r < 4; ++r)
        s[16 - U][r] += cond[r] ? shc[r] : shp[r];
    }
    shp = shc;
  }

  // per-row softmax, NO max-subtraction (|scores| ~ 1, exact in f32), exp2 domain.
  float wgt[4];
#pragma unroll
  for (int r = 0; r < 4; ++r) {
    float sum = 0.f;
#pragma unroll
    for (int t = 0; t < 17; ++t) {
      const float p = exp2f(s[t][r]);
      s[t][r] = p;
      sum += p;
    }
#pragma unroll
    for (int off = 1; off < 16; off <<= 1) sum += __shfl_xor(sum, off, 16);
    wgt[r] = v4[3 - r] * __builtin_amdgcn_rcpf(sum);  // v[n]/sum, n = n0+255-(16w+4g+r)
  }

  // out[m] += sum_i p * w : regs -> cross-group -> cross-wave (LDS) -> atomics
  __syncthreads();  // all waves done reading qu_sh; reuse as reduction buffer
#pragma unroll
  for (int t = 0; t < 17; ++t) {
    float y = s[t][0] * wgt[0] + s[t][1] * wgt[1] + s[t][2] * wgt[2] + s[t][3] * wgt[3];
    y += __shfl_xor(y, 16, 64);
    y += __shfl_xor(y, 32, 64);
    if (l < 16) red[w * NWP + 16 * t + c] = y;
  }
  __syncthreads();
  for (int m = tid; m < NW; m += 1024) {
    float ssum = 0.f;
#pragma unroll
    for (int ww = 0; ww < 16; ++ww) ssum += red[ww * NWP + m];
    atomicAdd(&out[((size_t)b * NW + m) * NH + h], ssum);
  }
}

extern "C" void kernel_launch(void* const* d_in, const int* in_sizes, int n_in,
                              void* d_out, int out_size, void* d_ws, size_t ws_size,
                              hipStream_t stream) {
  const float* x = (const float*)d_in[0];
  const float* Wq = (const float*)d_in[1];
  const float* bq = (const float*)d_in[2];
  const float* Wk = (const float*)d_in[3];
  const float* bk = (const float*)d_in[4];
  const float* Wv = (const float*)d_in[5];
  const float* dpe = (const float*)d_in[6];
  const float* u_pe = (const float*)d_in[7];
  const float* v_pe = (const float*)d_in[8];
  float* out = (float*)d_out;

  const size_t qk_elems = (size_t)NH * NB * NL * HD;  // 2,097,152
  float* vv = (float*)d_ws;                           // 65,536 f32
  unsigned short* qu = (unsigned short*)(vv + (size_t)NH * NB * NL);
  unsigned short* qv = qu + qk_elems;
  unsigned short* kb = qv + qk_elems;
  unsigned short* spt = kb + qk_elems;                // 8*272*32

  hipLaunchKernelGGL(projmm_kernel, dim3(PM_BLK + VV_BLK + SPE_BLK), dim3(256), 0, stream,
                     x, Wq, bq, Wk, bk, Wv, dpe, u_pe, v_pe, qu, qv, kb, vv, spt, out);
  hipLaunchKernelGGL(band_attn_mfma, dim3(NH * NB * (NL / ROWS)), dim3(1024), 0, stream,
                     qu, qv, kb, vv, spt, out);
}